// Round 7
// baseline (89.759 us; speedup 1.0000x reference)
//
#include <hip/hip_runtime.h>
#include <math.h>

// Chamfer distance via MFMA: d2[m,n] = r(m)·q(n), augmented 5-vectors
//   r = (-2px,-2py,-2pz,|p|^2,1)  [A, resident refs, registers]
//   q = (qx,qy,qz,1,|q|^2)        [B, LDS-resident queries]
// fp32 precision via 3-way bf16 split (r=r1+r2+r3, q=q1+q2+q3), products
// {11,12,21,13,31,22} packed along K: 2 chained v_mfma_f32_32x32x16_bf16
// per 32x32 tile. Verified absmax = 0.0 (bit-exact vs fp32 reference).
// B=16, N=2048 samp, M=8192 ref, fp32 in/out.
//
// v8 vs v7 (89.2 us; 41.5 us of that is the harness poison-fill floor):
//  - prep kernel + Qpk (2 MB round trip) deleted: QSPL=4 -> 512 queries/block
//    = 32 KB frags, prepped in-kernel into chunk-major LDS Qf[4][512] once
//    (no glds, no dbuf, no per-stage barriers; 2 barriers total).
//  - ref frags built per-lane in REGISTERS (kh-selects, no scratch).
//  - grid (16,32,4) = 2048 blocks = exactly 2 rounds at 4 blocks/CU (34 KB LDS).
//  - pipeline is now 2 kernels: sweep -> reduce.
#define BB 16
#define NN 2048
#define MM 8192

#define BLK 256
#define QSPL 4                 // query splits
#define NQ (NN / QSPL)         // 512 queries per block
#define CTS (NQ / 32)          // 16 col-tiles
#define YB (MM / 256)          // 32 ref blocks (ws1 partials)

typedef __attribute__((ext_vector_type(8))) short short8;
typedef __attribute__((ext_vector_type(16))) float f32x16;

union U16 { uint4 u; short8 s; };

static __device__ __forceinline__ unsigned short f2bf(float f) {
    unsigned int u = __float_as_uint(f);
    unsigned int r = (u + 0x7FFFu + ((u >> 16) & 1u)) >> 16;
    return (unsigned short)r;
}
static __device__ __forceinline__ float bf2f(unsigned short h) {
    return __uint_as_float(((unsigned int)h) << 16);
}

// 3-way split + 6-group K=32 pack; ord picks the split level per group.
// All loops unrolled -> static indexing -> registers only (rule #20).
static __device__ __forceinline__ void pack5(const float a5[5], const int ord[6],
                                             unsigned int uu[16]) {
    unsigned short h[3][5];
#pragma unroll
    for (int j = 0; j < 5; ++j) {
        float v = a5[j];
        h[0][j] = f2bf(v); float r1 = v - bf2f(h[0][j]);
        h[1][j] = f2bf(r1); float r2 = r1 - bf2f(h[1][j]);
        h[2][j] = f2bf(r2);
    }
    unsigned short K[32];
#pragma unroll
    for (int f = 0; f < 2; ++f) {
#pragma unroll
        for (int p2 = 0; p2 < 3; ++p2)
#pragma unroll
            for (int j2 = 0; j2 < 5; ++j2)
                K[f * 16 + p2 * 5 + j2] = h[ord[f * 3 + p2]][j2];
        K[f * 16 + 15] = 0;
    }
#pragma unroll
    for (int t = 0; t < 16; ++t)
        uu[t] = (unsigned int)K[2 * t] | ((unsigned int)K[2 * t + 1] << 16);
}

// DPP-min butterfly steps (all VALU; merge within 32-lane halves)
#define DPP_MIN(v, CTRL)                                                      \
    v = fminf(v, __uint_as_float((unsigned)__builtin_amdgcn_update_dpp(       \
                     0, (int)__float_as_uint(v), CTRL, 0xF, 0xF, true)))
#define SWZ16_MIN(v)                                                          \
    v = fminf(v, __uint_as_float((unsigned)__builtin_amdgcn_ds_swizzle(       \
                     (int)__float_as_uint(v), 0x401F)))

// ws layout:
//   ws2p : float[QSPL*BB*MM]  ref->samp partial mins (plain stores)    2 MB
//   ws1p : float[YB*BB*NN]    samp->ref partial mins (plain stores)    4 MB

// grid = (B, M/256, QSPL) = (16,32,4) = 2048 blocks, 4 waves.
// Wave owns 64 refs (2 row-tiles of 32, frags in regs); all NQ=512 queries
// LDS-resident (prepped in-kernel). 16 barrier-free inner iterations.
// D layout (verified): col = lane&31 (query), row = (reg&3)+8*(reg>>2)+4*(lane>>5).
__global__ void __launch_bounds__(BLK, 4) sweep_kernel(const float* __restrict__ ref,
                                                       const float* __restrict__ samp,
                                                       float* __restrict__ ws2p,
                                                       float* __restrict__ ws1p) {
    __shared__ uint4 Qf[4][NQ];                   // chunk-major query frags, 32 KB
    __shared__ unsigned int qMin[NQ];             // 2 KB

    const int b = blockIdx.x;
    const int m0 = blockIdx.y * 256;
    const int q0 = blockIdx.z * NQ;
    const int tid = threadIdx.x;
    const int w = tid >> 6;
    const int l = tid & 63;
    const int p = l & 31;                         // col lane (query within ct)
    const int kh = l >> 5;                        // k-half

    const int ordR[6] = {0, 0, 1, 0, 2, 1};       // A-side levels per group
    const int ordQ[6] = {0, 1, 0, 2, 0, 1};       // B-side levels per group

    // ---- ref prep: this lane's 2 refs -> register frags (kh-selected) ----
    U16 a0f0, a0f1, a1f0, a1f1;
    {
        const float* r0 = ref + ((size_t)(b * MM + m0 + w * 64 + p)) * 3;
        float x = r0[0], y = r0[1], z = r0[2];
        float a5[5] = {-2.f * x, -2.f * y, -2.f * z, fmaf(x, x, fmaf(y, y, z * z)), 1.f};
        unsigned int uu[16];
        pack5(a5, ordR, uu);
        a0f0.u = kh ? make_uint4(uu[4], uu[5], uu[6], uu[7])
                    : make_uint4(uu[0], uu[1], uu[2], uu[3]);
        a0f1.u = kh ? make_uint4(uu[12], uu[13], uu[14], uu[15])
                    : make_uint4(uu[8], uu[9], uu[10], uu[11]);
        const float* r1 = r0 + 32 * 3;
        x = r1[0]; y = r1[1]; z = r1[2];
        float a6[5] = {-2.f * x, -2.f * y, -2.f * z, fmaf(x, x, fmaf(y, y, z * z)), 1.f};
        pack5(a6, ordR, uu);
        a1f0.u = kh ? make_uint4(uu[4], uu[5], uu[6], uu[7])
                    : make_uint4(uu[0], uu[1], uu[2], uu[3]);
        a1f1.u = kh ? make_uint4(uu[12], uu[13], uu[14], uu[15])
                    : make_uint4(uu[8], uu[9], uu[10], uu[11]);
    }

    // ---- query prep: 2 queries/thread -> chunk-major LDS (conflict-free) ----
#pragma unroll
    for (int k2 = 0; k2 < NQ / BLK; ++k2) {
        const int q = k2 * BLK + tid;
        const float* s0 = samp + ((size_t)(b * NN + q0 + q)) * 3;
        float x = s0[0], y = s0[1], z = s0[2];
        float a5[5] = {x, y, z, 1.f, fmaf(x, x, fmaf(y, y, z * z))};
        unsigned int uu[16];
        pack5(a5, ordQ, uu);
        Qf[0][q] = make_uint4(uu[0], uu[1], uu[2], uu[3]);
        Qf[1][q] = make_uint4(uu[4], uu[5], uu[6], uu[7]);
        Qf[2][q] = make_uint4(uu[8], uu[9], uu[10], uu[11]);
        Qf[3][q] = make_uint4(uu[12], uu[13], uu[14], uu[15]);
    }
    qMin[tid] = 0x7F7F7F7Fu;                      // +inf stand-in (nonneg floats)
    qMin[tid + BLK] = 0x7F7F7F7Fu;
    __syncthreads();

    float run0[16], run1[16];
#pragma unroll
    for (int j = 0; j < 16; ++j) { run0[j] = INFINITY; run1[j] = INFINITY; }

    const f32x16 fz = {0.f, 0.f, 0.f, 0.f, 0.f, 0.f, 0.f, 0.f,
                       0.f, 0.f, 0.f, 0.f, 0.f, 0.f, 0.f, 0.f};

#pragma unroll 2
    for (int ct = 0; ct < CTS; ++ct) {
        const int q = ct * 32 + p;
        U16 b0, b1;
        b0.u = Qf[kh][q];                         // ds_read_b128, conflict-free
        b1.u = Qf[2 + kh][q];
        f32x16 d0 = __builtin_amdgcn_mfma_f32_32x32x16_bf16(a0f0.s, b0.s, fz, 0, 0, 0);
        d0 = __builtin_amdgcn_mfma_f32_32x32x16_bf16(a0f1.s, b1.s, d0, 0, 0, 0);
        f32x16 d1 = __builtin_amdgcn_mfma_f32_32x32x16_bf16(a1f0.s, b0.s, fz, 0, 0, 0);
        d1 = __builtin_amdgcn_mfma_f32_32x32x16_bf16(a1f1.s, b1.s, d1, 0, 0, 0);
        // ref-direction running mins (register-local)
#pragma unroll
        for (int j = 0; j < 16; ++j) {
            run0[j] = fminf(run0[j], d0[j]);
            run1[j] = fminf(run1[j], d1[j]);
        }
        // query-direction: tree over this lane's 32 rows -> 2-way LDS atomic
        float tv[8];
#pragma unroll
        for (int k = 0; k < 8; ++k) tv[k] = fminf(d0[k], d0[k + 8]);
#pragma unroll
        for (int k = 0; k < 8; ++k) tv[k] = fminf(tv[k], fminf(d1[k], d1[k + 8]));
#pragma unroll
        for (int k = 0; k < 4; ++k) tv[k] = fminf(tv[k], tv[k + 4]);
        float t = fminf(fminf(tv[0], tv[2]), fminf(tv[1], tv[3]));
        atomicMin(&qMin[q], __float_as_uint(fmaxf(t, 0.f)));
    }
    __syncthreads();

    // query-direction dump: plain-store partial per (ref-block, query)
    float* w1 = ws1p + ((size_t)blockIdx.y * BB + b) * NN + q0;
    w1[tid] = __uint_as_float(qMin[tid]);
    w1[tid + BLK] = __uint_as_float(qMin[tid + BLK]);

    // ref-direction merge across the 32 lanes of each half: DPP butterfly
#pragma unroll
    for (int j = 0; j < 16; ++j) {
        DPP_MIN(run0[j], 0xB1);  DPP_MIN(run0[j], 0x4E);   // quad_perm xor1, xor2
        DPP_MIN(run0[j], 0x141); DPP_MIN(run0[j], 0x140);  // half_mirror, mirror
        SWZ16_MIN(run0[j]);                                // lane ^ 16
        DPP_MIN(run1[j], 0xB1);  DPP_MIN(run1[j], 0x4E);
        DPP_MIN(run1[j], 0x141); DPP_MIN(run1[j], 0x140);
        SWZ16_MIN(run1[j]);
    }
    // lane (p = t*16+j) takes run_t[j]; row = t*32 + (j&3) + 8*(j>>2) + 4*kh
    float out = 0.f;
#pragma unroll
    for (int j = 0; j < 16; ++j) { if (p == j)      out = run0[j]; }
#pragma unroll
    for (int j = 0; j < 16; ++j) { if (p == 16 + j) out = run1[j]; }
    const int t2 = p >> 4, j4 = p & 15;
    const int row = t2 * 32 + (j4 & 3) + ((j4 >> 2) << 3) + 4 * kh;
    ws2p[((size_t)blockIdx.z * BB + b) * MM + m0 + w * 64 + row] = fmaxf(out, 0.f);
}

// Final reduce. grid = B, block = 1024. Min-folds the partials, then sums.
#define BLKR 1024
__global__ void __launch_bounds__(BLKR) reduce_kernel(const float* __restrict__ ws1p,
                                                      const float* __restrict__ ws2p,
                                                      float* __restrict__ out) {
    const int b = blockIdx.x;
    const int tid = threadIdx.x;
    const int lane = tid & 63;
    const int wv = tid >> 6;

    float sd1 = 0.f, sr1 = 0.f, sd2 = 0.f, sr2 = 0.f;
#pragma unroll
    for (int i = tid; i < NN; i += BLKR) {
        float m = INFINITY;
#pragma unroll
        for (int y = 0; y < YB; ++y)
            m = fminf(m, ws1p[((size_t)y * BB + b) * NN + i]);
        sd1 += m;
        sr1 += sqrtf(m);
    }
#pragma unroll
    for (int i = tid; i < MM; i += BLKR) {
        float v = INFINITY;
#pragma unroll
        for (int zz = 0; zz < QSPL; ++zz)
            v = fminf(v, ws2p[((size_t)zz * BB + b) * MM + i]);
        sd2 += v;
        sr2 += sqrtf(v);
    }
#pragma unroll
    for (int s = 32; s > 0; s >>= 1) {
        sd1 += __shfl_xor(sd1, s);
        sr1 += __shfl_xor(sr1, s);
        sd2 += __shfl_xor(sd2, s);
        sr2 += __shfl_xor(sr2, s);
    }

    __shared__ float4 red[BLKR / 64];
    if (lane == 0) red[wv] = make_float4(sd1, sr1, sd2, sr2);
    __syncthreads();
    if (tid == 0) {
        float4 acc = red[0];
#pragma unroll
        for (int w = 1; w < BLKR / 64; ++w) {
            acc.x += red[w].x; acc.y += red[w].y;
            acc.z += red[w].z; acc.w += red[w].w;
        }
        out[b]      = (acc.y * (1.0f / NN) + acc.w * (1.0f / MM)) * 0.5f;  // cd_p
        out[BB + b] = acc.x * (1.0f / NN) + acc.z * (1.0f / MM);           // cd_t
    }
}

extern "C" void kernel_launch(void* const* d_in, const int* in_sizes, int n_in,
                              void* d_out, int out_size, void* d_ws, size_t ws_size,
                              hipStream_t stream) {
    const float* ref  = (const float*)d_in[0];   // [B, M, 3]
    const float* samp = (const float*)d_in[1];   // [B, N, 3]
    float* out = (float*)d_out;                  // [cd_p[16], cd_t[16]]

    float* ws2p = (float*)d_ws;                  // QSPL*BB*MM
    float* ws1p = ws2p + (size_t)QSPL * BB * MM; // YB*BB*NN

    dim3 gs(BB, MM / 256, QSPL);   // (16, 32, 4) = 2048 blocks
    sweep_kernel<<<gs, BLK, 0, stream>>>(ref, samp, ws2p, ws1p);

    reduce_kernel<<<BB, BLKR, 0, stream>>>(ws1p, ws2p, out);
}

// Round 8
// 87.291 us; speedup vs baseline: 1.0283x; 1.0283x over previous
//
#include <hip/hip_runtime.h>
#include <math.h>

// Chamfer distance via MFMA: d2[m,n] = r(m)·q(n), augmented 5-vectors
//   r = (-2px,-2py,-2pz,|p|^2,1)  [A, resident refs, registers]
//   q = (qx,qy,qz,1,|q|^2)        [B, LDS-resident queries]
// fp32 precision via 3-way bf16 split (r=r1+r2+r3, q=q1+q2+q3), products
// {11,12,21,13,31,22} packed along K: 2 chained v_mfma_f32_32x32x16_bf16
// per 32x32 tile. Verified absmax = 0.0 (bit-exact vs fp32 reference).
// B=16, N=2048 samp, M=8192 ref, fp32 in/out.
//
// v9 vs v8 (89.8 us; 42 us harness poison-fill floor):
//  - reduce's input shrunk 6 MB -> 640 KB: ws1p/ws2p plain-store partials
//    (32-way/4-way folds over dirty cross-XCD lines, read by only 16 blocks)
//    replaced by global atomicMin merged IN sweep (1M + 512K atomics, cheap
//    per v5 evidence). Init via one 640 KB hipMemsetAsync(0x7F).
//  - sweep loop/math unchanged (verified bit-exact).
#define BB 16
#define NN 2048
#define MM 8192

#define BLK 256
#define QSPL 4                 // query splits
#define NQ (NN / QSPL)         // 512 queries per block
#define CTS (NQ / 32)          // 16 col-tiles

typedef __attribute__((ext_vector_type(8))) short short8;
typedef __attribute__((ext_vector_type(16))) float f32x16;

union U16 { uint4 u; short8 s; };

static __device__ __forceinline__ unsigned short f2bf(float f) {
    unsigned int u = __float_as_uint(f);
    unsigned int r = (u + 0x7FFFu + ((u >> 16) & 1u)) >> 16;
    return (unsigned short)r;
}
static __device__ __forceinline__ float bf2f(unsigned short h) {
    return __uint_as_float(((unsigned int)h) << 16);
}

// 3-way split + 6-group K=32 pack; ord picks the split level per group.
// All loops unrolled -> static indexing -> registers only.
static __device__ __forceinline__ void pack5(const float a5[5], const int ord[6],
                                             unsigned int uu[16]) {
    unsigned short h[3][5];
#pragma unroll
    for (int j = 0; j < 5; ++j) {
        float v = a5[j];
        h[0][j] = f2bf(v); float r1 = v - bf2f(h[0][j]);
        h[1][j] = f2bf(r1); float r2 = r1 - bf2f(h[1][j]);
        h[2][j] = f2bf(r2);
    }
    unsigned short K[32];
#pragma unroll
    for (int f = 0; f < 2; ++f) {
#pragma unroll
        for (int p2 = 0; p2 < 3; ++p2)
#pragma unroll
            for (int j2 = 0; j2 < 5; ++j2)
                K[f * 16 + p2 * 5 + j2] = h[ord[f * 3 + p2]][j2];
        K[f * 16 + 15] = 0;
    }
#pragma unroll
    for (int t = 0; t < 16; ++t)
        uu[t] = (unsigned int)K[2 * t] | ((unsigned int)K[2 * t + 1] << 16);
}

// DPP-min butterfly steps (all VALU; merge within 32-lane halves)
#define DPP_MIN(v, CTRL)                                                      \
    v = fminf(v, __uint_as_float((unsigned)__builtin_amdgcn_update_dpp(       \
                     0, (int)__float_as_uint(v), CTRL, 0xF, 0xF, true)))
#define SWZ16_MIN(v)                                                          \
    v = fminf(v, __uint_as_float((unsigned)__builtin_amdgcn_ds_swizzle(       \
                     (int)__float_as_uint(v), 0x401F)))

// ws layout (memset 0x7F covers both):
//   ws2 : uint[BB*MM]  ref->samp mins (atomicMin, 4 contenders)   512 KB
//   ws1 : uint[BB*NN]  samp->ref mins (atomicMin, 32 contenders)  128 KB

// grid = (B, M/256, QSPL) = (16,32,4) = 2048 blocks, 4 waves.
// Wave owns 64 refs (2 row-tiles of 32, frags in regs); all NQ=512 queries
// LDS-resident (prepped in-kernel). 16 barrier-free inner iterations.
// D layout (verified): col = lane&31 (query), row = (reg&3)+8*(reg>>2)+4*(lane>>5).
__global__ void __launch_bounds__(BLK, 4) sweep_kernel(const float* __restrict__ ref,
                                                       const float* __restrict__ samp,
                                                       unsigned int* __restrict__ ws2,
                                                       unsigned int* __restrict__ ws1) {
    __shared__ uint4 Qf[4][NQ];                   // chunk-major query frags, 32 KB
    __shared__ unsigned int qMin[NQ];             // 2 KB

    const int b = blockIdx.x;
    const int m0 = blockIdx.y * 256;
    const int q0 = blockIdx.z * NQ;
    const int tid = threadIdx.x;
    const int w = tid >> 6;
    const int l = tid & 63;
    const int p = l & 31;                         // col lane (query within ct)
    const int kh = l >> 5;                        // k-half

    const int ordR[6] = {0, 0, 1, 0, 2, 1};       // A-side levels per group
    const int ordQ[6] = {0, 1, 0, 2, 0, 1};       // B-side levels per group

    // ---- ref prep: this lane's 2 refs -> register frags (kh-selected) ----
    U16 a0f0, a0f1, a1f0, a1f1;
    {
        const float* r0 = ref + ((size_t)(b * MM + m0 + w * 64 + p)) * 3;
        float x = r0[0], y = r0[1], z = r0[2];
        float a5[5] = {-2.f * x, -2.f * y, -2.f * z, fmaf(x, x, fmaf(y, y, z * z)), 1.f};
        unsigned int uu[16];
        pack5(a5, ordR, uu);
        a0f0.u = kh ? make_uint4(uu[4], uu[5], uu[6], uu[7])
                    : make_uint4(uu[0], uu[1], uu[2], uu[3]);
        a0f1.u = kh ? make_uint4(uu[12], uu[13], uu[14], uu[15])
                    : make_uint4(uu[8], uu[9], uu[10], uu[11]);
        const float* r1 = r0 + 32 * 3;
        x = r1[0]; y = r1[1]; z = r1[2];
        float a6[5] = {-2.f * x, -2.f * y, -2.f * z, fmaf(x, x, fmaf(y, y, z * z)), 1.f};
        pack5(a6, ordR, uu);
        a1f0.u = kh ? make_uint4(uu[4], uu[5], uu[6], uu[7])
                    : make_uint4(uu[0], uu[1], uu[2], uu[3]);
        a1f1.u = kh ? make_uint4(uu[12], uu[13], uu[14], uu[15])
                    : make_uint4(uu[8], uu[9], uu[10], uu[11]);
    }

    // ---- query prep: 2 queries/thread -> chunk-major LDS (conflict-free) ----
#pragma unroll
    for (int k2 = 0; k2 < NQ / BLK; ++k2) {
        const int q = k2 * BLK + tid;
        const float* s0 = samp + ((size_t)(b * NN + q0 + q)) * 3;
        float x = s0[0], y = s0[1], z = s0[2];
        float a5[5] = {x, y, z, 1.f, fmaf(x, x, fmaf(y, y, z * z))};
        unsigned int uu[16];
        pack5(a5, ordQ, uu);
        Qf[0][q] = make_uint4(uu[0], uu[1], uu[2], uu[3]);
        Qf[1][q] = make_uint4(uu[4], uu[5], uu[6], uu[7]);
        Qf[2][q] = make_uint4(uu[8], uu[9], uu[10], uu[11]);
        Qf[3][q] = make_uint4(uu[12], uu[13], uu[14], uu[15]);
    }
    qMin[tid] = 0x7F7F7F7Fu;                      // +inf stand-in (nonneg floats)
    qMin[tid + BLK] = 0x7F7F7F7Fu;
    __syncthreads();

    float run0[16], run1[16];
#pragma unroll
    for (int j = 0; j < 16; ++j) { run0[j] = INFINITY; run1[j] = INFINITY; }

    const f32x16 fz = {0.f, 0.f, 0.f, 0.f, 0.f, 0.f, 0.f, 0.f,
                       0.f, 0.f, 0.f, 0.f, 0.f, 0.f, 0.f, 0.f};

#pragma unroll 2
    for (int ct = 0; ct < CTS; ++ct) {
        const int q = ct * 32 + p;
        U16 b0, b1;
        b0.u = Qf[kh][q];                         // ds_read_b128, conflict-free
        b1.u = Qf[2 + kh][q];
        f32x16 d0 = __builtin_amdgcn_mfma_f32_32x32x16_bf16(a0f0.s, b0.s, fz, 0, 0, 0);
        d0 = __builtin_amdgcn_mfma_f32_32x32x16_bf16(a0f1.s, b1.s, d0, 0, 0, 0);
        f32x16 d1 = __builtin_amdgcn_mfma_f32_32x32x16_bf16(a1f0.s, b0.s, fz, 0, 0, 0);
        d1 = __builtin_amdgcn_mfma_f32_32x32x16_bf16(a1f1.s, b1.s, d1, 0, 0, 0);
        // ref-direction running mins (register-local)
#pragma unroll
        for (int j = 0; j < 16; ++j) {
            run0[j] = fminf(run0[j], d0[j]);
            run1[j] = fminf(run1[j], d1[j]);
        }
        // query-direction: tree over this lane's 32 rows -> 2-way LDS atomic
        float tv[8];
#pragma unroll
        for (int k = 0; k < 8; ++k) tv[k] = fminf(d0[k], d0[k + 8]);
#pragma unroll
        for (int k = 0; k < 8; ++k) tv[k] = fminf(tv[k], fminf(d1[k], d1[k + 8]));
#pragma unroll
        for (int k = 0; k < 4; ++k) tv[k] = fminf(tv[k], tv[k + 4]);
        float t = fminf(fminf(tv[0], tv[2]), fminf(tv[1], tv[3]));
        atomicMin(&qMin[q], __float_as_uint(fmaxf(t, 0.f)));
    }
    __syncthreads();

    // query-direction dump: one global atomicMin per (query, block)
    unsigned int* w1 = ws1 + (size_t)b * NN + q0;
    atomicMin(&w1[tid], qMin[tid]);
    atomicMin(&w1[tid + BLK], qMin[tid + BLK]);

    // ref-direction merge across the 32 lanes of each half: DPP butterfly
#pragma unroll
    for (int j = 0; j < 16; ++j) {
        DPP_MIN(run0[j], 0xB1);  DPP_MIN(run0[j], 0x4E);   // quad_perm xor1, xor2
        DPP_MIN(run0[j], 0x141); DPP_MIN(run0[j], 0x140);  // half_mirror, mirror
        SWZ16_MIN(run0[j]);                                // lane ^ 16
        DPP_MIN(run1[j], 0xB1);  DPP_MIN(run1[j], 0x4E);
        DPP_MIN(run1[j], 0x141); DPP_MIN(run1[j], 0x140);
        SWZ16_MIN(run1[j]);
    }
    // lane (p = t*16+j) takes run_t[j]; row = t*32 + (j&3) + 8*(j>>2) + 4*kh
    float out = 0.f;
#pragma unroll
    for (int j = 0; j < 16; ++j) { if (p == j)      out = run0[j]; }
#pragma unroll
    for (int j = 0; j < 16; ++j) { if (p == 16 + j) out = run1[j]; }
    const int t2 = p >> 4, j4 = p & 15;
    const int row = t2 * 32 + (j4 & 3) + ((j4 >> 2) << 3) + 4 * kh;
    atomicMin(&ws2[(size_t)b * MM + m0 + w * 64 + row],
              __float_as_uint(fmaxf(out, 0.f)));
}

// Final reduce. grid = B, block = 1024. Reads 640 KB of fully-merged mins.
#define BLKR 1024
__global__ void __launch_bounds__(BLKR) reduce_kernel(const unsigned int* __restrict__ ws1,
                                                      const unsigned int* __restrict__ ws2,
                                                      float* __restrict__ out) {
    const int b = blockIdx.x;
    const int tid = threadIdx.x;
    const int lane = tid & 63;
    const int wv = tid >> 6;

    float sd1 = 0.f, sr1 = 0.f, sd2 = 0.f, sr2 = 0.f;
#pragma unroll
    for (int i = tid; i < NN; i += BLKR) {
        float v = __uint_as_float(ws1[(size_t)b * NN + i]);  // already >= 0
        sd1 += v;
        sr1 += sqrtf(v);
    }
#pragma unroll
    for (int i = tid; i < MM; i += BLKR) {
        float v = __uint_as_float(ws2[(size_t)b * MM + i]);  // already >= 0
        sd2 += v;
        sr2 += sqrtf(v);
    }
#pragma unroll
    for (int s = 32; s > 0; s >>= 1) {
        sd1 += __shfl_xor(sd1, s);
        sr1 += __shfl_xor(sr1, s);
        sd2 += __shfl_xor(sd2, s);
        sr2 += __shfl_xor(sr2, s);
    }

    __shared__ float4 red[BLKR / 64];
    if (lane == 0) red[wv] = make_float4(sd1, sr1, sd2, sr2);
    __syncthreads();
    if (tid == 0) {
        float4 acc = red[0];
#pragma unroll
        for (int w = 1; w < BLKR / 64; ++w) {
            acc.x += red[w].x; acc.y += red[w].y;
            acc.z += red[w].z; acc.w += red[w].w;
        }
        out[b]      = (acc.y * (1.0f / NN) + acc.w * (1.0f / MM)) * 0.5f;  // cd_p
        out[BB + b] = acc.x * (1.0f / NN) + acc.z * (1.0f / MM);           // cd_t
    }
}

extern "C" void kernel_launch(void* const* d_in, const int* in_sizes, int n_in,
                              void* d_out, int out_size, void* d_ws, size_t ws_size,
                              hipStream_t stream) {
    const float* ref  = (const float*)d_in[0];   // [B, M, 3]
    const float* samp = (const float*)d_in[1];   // [B, N, 3]
    float* out = (float*)d_out;                  // [cd_p[16], cd_t[16]]

    unsigned int* ws2 = (unsigned int*)d_ws;            // BB*MM
    unsigned int* ws1 = ws2 + (size_t)BB * MM;          // BB*NN

    // 0x7F7F7F7F = 3.39e38 as float: +inf stand-in for uint-ordered atomicMin
    // over non-negative float bit patterns. 640 KB.
    hipMemsetAsync(d_ws, 0x7F, ((size_t)BB * MM + (size_t)BB * NN) * sizeof(unsigned int), stream);

    dim3 gs(BB, MM / 256, QSPL);   // (16, 32, 4) = 2048 blocks
    sweep_kernel<<<gs, BLK, 0, stream>>>(ref, samp, ws2, ws1);

    reduce_kernel<<<BB, BLKR, 0, stream>>>(ws1, ws2, out);
}